// Round 9
// baseline (350.578 us; speedup 1.0000x reference)
//
#include <hip/hip_runtime.h>
#include <math.h>

// Problem constants (fixed by setup_inputs)
#define B_   4
#define L_   512
#define D_   768
#define K_   10
#define P_   50
#define R_   1586          // 2*D + P
#define NP_  10642         // number of window pairs
#define MROWS 2048         // B_*L_
#define NPAD 1664          // 13*128, padded N for MFMA tiles
#define UVS  1600          // bf16 row stride for U/V/F (3200 B, 16B-aligned)

// out layout: pred [B,n] | emo_cau_pos [n,2] | h [B,n,R]  (all as float)
#define PRED_OFF 0
#define POS_OFF  (B_ * NP_)
#define H_OFF    (B_ * NP_ + NP_ * 2)

typedef __attribute__((ext_vector_type(8))) short short8;    // 8 bf16 (MFMA A/B frag)
typedef __attribute__((ext_vector_type(4))) float floatx4;   // MFMA C/D frag

__device__ __forceinline__ unsigned short f2bf(float f) {
    union { float f; unsigned int u; } a; a.f = f;
    unsigned int u = a.u;
    return (unsigned short)((u + 0x7FFF + ((u >> 16) & 1)) >> 16);  // RNE
}
__device__ __forceinline__ float bf2f(unsigned short u) {
    union { unsigned int u; float f; } a; a.u = ((unsigned int)u) << 16;
    return a.f;
}

// ---- closed-form pair indexing ----
__device__ __forceinline__ int pair_offset(int i) {
    int h = i < K_ ? i : K_;
    int off = h * (K_ + 1) + (h * (h - 1)) / 2;
    if (i > K_) {
        int fullEnd = i < (L_ - K_) ? i : (L_ - K_);
        off += (fullEnd - K_) * (2 * K_ + 1);
        if (i > L_ - K_) {
            int t = i - (L_ - K_);
            int first = 2 * K_;
            int last = L_ + K_ - (i - 1);
            off += (first + last) * t / 2;
        }
    }
    return off;
}

// ========= merged prep: convert_A | convert_W | build_F | pos =============
#define CA_BLOCKS 1536      // MROWS*D_/1024
#define CW_BLOCKS 2496      // 24*52*2
#define PREP_GRID (CA_BLOCKS + CW_BLOCKS + 21 + 2)
__global__ __launch_bounds__(256) void prep(
        const float* __restrict__ doc, const float* __restrict__ pos_emb,
        const float* __restrict__ W1, const float* __restrict__ b1,
        unsigned short* __restrict__ At, unsigned short* __restrict__ Wt,
        unsigned short* __restrict__ Fb, float* __restrict__ out) {
    __shared__ float tile[32][33];
    __shared__ float Es[P_];
    const int bid = blockIdx.x;

    if (bid < CA_BLOCKS) {                       // ---- doc -> bf16 [2048][768]
        int idx = (bid * 256 + threadIdx.x) * 4;
        float4 v = *(const float4*)(doc + idx);
        ushort4 o;
        o.x = f2bf(v.x); o.y = f2bf(v.y); o.z = f2bf(v.z); o.w = f2bf(v.w);
        *(ushort4*)(At + idx) = o;
        return;
    }
    if (bid < CA_BLOCKS + CW_BLOCKS) {           // ---- W1 -> Wt[z][n][k] bf16
        int bb = bid - CA_BLOCKS;
        int z = bb / 1248, rem = bb % 1248;
        int k0 = (rem % 24) * 32;
        int n0 = (rem / 24) * 32;
        int tx = threadIdx.x & 31, ty = threadIdx.x >> 5;
        #pragma unroll
        for (int r = 0; r < 4; ++r) {
            int k = k0 + ty + r * 8;
            int n = n0 + tx;
            tile[ty + r * 8][tx] = (n < R_) ? W1[(size_t)(z * D_ + k) * R_ + n] : 0.f;
        }
        __syncthreads();
        #pragma unroll
        for (int r = 0; r < 4; ++r) {
            int n = n0 + ty + r * 8;
            int k = k0 + tx;
            Wt[(size_t)z * NPAD * D_ + (size_t)n * D_ + k] = f2bf(tile[tx][ty + r * 8]);
        }
        return;
    }
    if (bid < CA_BLOCKS + CW_BLOCKS + 21) {      // ---- F = E @ W1[1536:,:] + b1
        int s = bid - (CA_BLOCKS + CW_BLOCKS);
        if (threadIdx.x < P_) {
            float acc = 0.f;
            #pragma unroll
            for (int r = 0; r <= 2 * K_; ++r) {
                float cnt = (float)(L_ - (r > K_ ? r - K_ : K_ - r));
                float d = (float)(s - r);
                acc += cnt * expf(-d * d) * pos_emb[r * P_ + threadIdx.x];
            }
            Es[threadIdx.x] = acc;
        }
        __syncthreads();
        for (int j = threadIdx.x; j < R_; j += 256) {
            float acc = b1[j];
            #pragma unroll 10
            for (int p = 0; p < P_; ++p)
                acc += Es[p] * W1[(2 * D_ + p) * R_ + j];
            Fb[s * UVS + j] = f2bf(acc);
        }
        return;
    }
    // ---- pos: emo_cau_pos [n,2], thread = sentence i
    int i = (bid - (CA_BLOCKS + CW_BLOCKS + 21)) * 256 + threadIdx.x;
    if (i < L_) {
        int poff = pair_offset(i);
        int jmin = i - K_ > 0 ? i - K_ : 0;
        int jmax = i + K_ < L_ - 1 ? i + K_ : L_ - 1;
        for (int j = jmin; j <= jmax; ++j) {
            int p = poff + (j - jmin);
            out[POS_OFF + p * 2 + 0] = (float)(i + 1);
            out[POS_OFF + p * 2 + 1] = (float)(j + 1);
        }
    }
}

// ===== MFMA GEMM: BK=64, dbuf + counted vmcnt + XOR swizzle + XCD locality
// (unchanged from round 6 — best measured)
#define GLOAD_LDS16(g, l) __builtin_amdgcn_global_load_lds( \
    (const __attribute__((address_space(1))) void*)(g), \
    (__attribute__((address_space(3))) void*)(l), 16, 0, 0)

__global__ __launch_bounds__(256) void gemm_mfma(
        const unsigned short* __restrict__ At,   // [2048][768] bf16
        const unsigned short* __restrict__ Wt,   // [2][1664][768] bf16 (B^T)
        unsigned short* __restrict__ U, unsigned short* __restrict__ V) {
    __shared__ unsigned short Alds[2][128 * 64];   // 2 x 16 KB
    __shared__ unsigned short Blds[2][128 * 64];

    // hardware round-robins consecutive blockIdx across XCDs: bid%8 = XCD
    const int sw  = (blockIdx.x & 7) * 52 + (blockIdx.x >> 3);   // bijective
    const int z   = sw / 208;
    const int rem = sw % 208;
    const int tileN = (rem / 16) * 128;
    const int tileM = (rem % 16) * 128;
    const unsigned short* Bt = Wt + (size_t)z * NPAD * D_;
    unsigned short* C = z ? V : U;

    const int lane = threadIdx.x & 63;
    const int w = threadIdx.x >> 6;
    const int wm = (w & 1) * 64, wn = (w >> 1) * 64;
    const int quad = lane >> 4, l16 = lane & 15;

    floatx4 acc[4][4] = {};

#define STAGE(buf, kk) do { \
        _Pragma("unroll") \
        for (int t = 0; t < 4; ++t) { \
            int chunk = t * 4 + w;               /* 0..15, wave-uniform */ \
            int r = chunk * 8 + (lane >> 3); \
            int sl = (lane & 7) ^ (lane >> 3);   /* pre-swizzled source slot */ \
            GLOAD_LDS16(At + (size_t)(tileM + r) * D_ + (kk) + sl * 8, \
                        &Alds[buf][chunk * 512]); \
            GLOAD_LDS16(Bt + (size_t)(tileN + r) * D_ + (kk) + sl * 8, \
                        &Blds[buf][chunk * 512]); \
        } } while (0)

#define KSTEP(rb, kk, dopf) do { \
        if (dopf) { \
            STAGE(rb ^ 1, (kk) + 64); \
            asm volatile("s_waitcnt vmcnt(8)" ::: "memory"); \
        } else { \
            asm volatile("s_waitcnt vmcnt(0)" ::: "memory"); \
        } \
        __builtin_amdgcn_s_barrier(); \
        __builtin_amdgcn_sched_barrier(0); \
        short8 a[4][2], b[4][2]; \
        _Pragma("unroll") \
        for (int im = 0; im < 4; ++im) \
            _Pragma("unroll") \
            for (int ks = 0; ks < 2; ++ks) \
                a[im][ks] = *(const short8*)&Alds[rb][ \
                    (wm + im * 16 + l16) * 64 + \
                    (((ks * 4 + quad) ^ (l16 & 7)) * 8)]; \
        _Pragma("unroll") \
        for (int in = 0; in < 4; ++in) \
            _Pragma("unroll") \
            for (int ks = 0; ks < 2; ++ks) \
                b[in][ks] = *(const short8*)&Blds[rb][ \
                    (wn + in * 16 + l16) * 64 + \
                    (((ks * 4 + quad) ^ (l16 & 7)) * 8)]; \
        _Pragma("unroll") \
        for (int im = 0; im < 4; ++im) \
            _Pragma("unroll") \
            for (int in = 0; in < 4; ++in) \
                _Pragma("unroll") \
                for (int ks = 0; ks < 2; ++ks) \
                    acc[im][in] = __builtin_amdgcn_mfma_f32_16x16x32_bf16( \
                        a[im][ks], b[in][ks], acc[im][in], 0, 0, 0); \
        __builtin_amdgcn_sched_barrier(0); \
        __builtin_amdgcn_s_barrier(); \
    } while (0)

    STAGE(0, 0);
    for (int k0 = 0; k0 < D_; k0 += 128) {       // 6 iters x 2 = 12 K-steps
        KSTEP(0, k0, true);
        KSTEP(1, k0 + 64, (k0 + 128) < D_);
    }
#undef KSTEP
#undef STAGE

    #pragma unroll
    for (int im = 0; im < 4; ++im) {
        #pragma unroll
        for (int in = 0; in < 4; ++in) {
            int col = tileN + wn + in * 16 + l16;
            if (col < R_) {
                #pragma unroll
                for (int r = 0; r < 4; ++r) {
                    int row = tileM + wm + im * 16 + quad * 4 + r;
                    C[(size_t)row * UVS + col] = f2bf(acc[im][in][r]);
                }
            }
        }
    }
}

// ==== epilogue: one BLOCK per (b,i), XCD swizzle; wave w: dj = w, w+4, ...
// T14 reg-prefetch on BOTH V and F rows; U and W2 persistent in registers;
// stores parity-split (even rows 2xfloat4; odd rows f2,f4,f2); pos writes
// moved to prep.
#define NG 4
__global__ __launch_bounds__(256) void epilogue(
        const unsigned short* __restrict__ U, const unsigned short* __restrict__ V,
        const unsigned short* __restrict__ Fb, const float* __restrict__ W2,
        const float* __restrict__ b2, float* __restrict__ out) {
    const int w    = threadIdx.x >> 6;
    const int lane = threadIdx.x & 63;
    const int sw   = (blockIdx.x & 7) * 256 + (blockIdx.x >> 3);  // bijective
    const int b    = sw >> 9;                 // /L_
    const int i    = sw & (L_ - 1);

    const unsigned short* vbase = V + (size_t)(b * L_) * UVS;
    const unsigned short* urow  = U + (size_t)(b * L_ + i) * UVS;

    // per-lane element group offsets (lane owns 8 consecutive elems)
    const int c0 = lane, c1 = lane + 64, c2 = lane + 128, c3 = lane + 192;
    const int off3 = c3 < 198 ? 8 * c3 : 1584;   // clamped tail offset

    // ---- prefetch first dj's V and F rows (hide under U/W2 preload) ----
    int j0 = i - K_ + w;
    int jc0 = j0 < 0 ? 0 : (j0 > L_ - 1 ? L_ - 1 : j0);
    short8 nv0, nv1, nv2, nv3, nf0, nf1, nf2, nf3;
    {
        const unsigned short* vr = vbase + (size_t)jc0 * UVS;
        const unsigned short* fr = Fb + (size_t)w * UVS;
        nv0 = *(const short8*)(vr + 8 * c0);
        nv1 = *(const short8*)(vr + 8 * c1);
        nv2 = *(const short8*)(vr + 8 * c2);
        nv3 = *(const short8*)(vr + off3);
        nf0 = *(const short8*)(fr + 8 * c0);
        nf1 = *(const short8*)(fr + 8 * c1);
        nf2 = *(const short8*)(fr + 8 * c2);
        nf3 = *(const short8*)(fr + off3);
    }

    // persistent U (f32) and W2 caches
    float uf[NG][8], wf[NG][8];
    #pragma unroll
    for (int t = 0; t < NG; ++t) {
        int c = lane + t * 64;
        if (c < 198) {
            short8 uu = *(const short8*)(urow + 8 * c);
            float4 wa = *(const float4*)(W2 + 8 * c);
            float4 wb = *(const float4*)(W2 + 8 * c + 4);
            #pragma unroll
            for (int e = 0; e < 8; ++e) uf[t][e] = bf2f((unsigned short)uu[e]);
            wf[t][0] = wa.x; wf[t][1] = wa.y; wf[t][2] = wa.z; wf[t][3] = wa.w;
            wf[t][4] = wb.x; wf[t][5] = wb.y; wf[t][6] = wb.z; wf[t][7] = wb.w;
        } else if (c == 198) {
            ushort2 uu = *(const ushort2*)(urow + 1584);
            float2 wt = *(const float2*)(W2 + 1584);
            uf[t][0] = bf2f(uu.x); uf[t][1] = bf2f(uu.y);
            wf[t][0] = wt.x;       wf[t][1] = wt.y;
        }
    }

    const int base = i - K_ > 0 ? i - K_ : 0;
    const int poff = pair_offset(i);
    const float bias = b2[0];

    #pragma unroll 1
    for (int dj = w; dj < 2 * K_ + 1; dj += 4) {
        int j = i - K_ + dj;

        // rotate prefetched rows into "current"
        short8 cv0 = nv0, cv1 = nv1, cv2 = nv2, cv3 = nv3;
        short8 cf0 = nf0, cf1 = nf1, cf2 = nf2, cf3 = nf3;

        // issue next dj's prefetch (wave-uniform branch)
        int djn = dj + 4;
        if (djn < 2 * K_ + 1) {
            int jn = i - K_ + djn;
            int jcn = jn < 0 ? 0 : (jn > L_ - 1 ? L_ - 1 : jn);
            const unsigned short* vr = vbase + (size_t)jcn * UVS;
            const unsigned short* fr = Fb + (size_t)djn * UVS;
            nv0 = *(const short8*)(vr + 8 * c0);
            nv1 = *(const short8*)(vr + 8 * c1);
            nv2 = *(const short8*)(vr + 8 * c2);
            nv3 = *(const short8*)(vr + off3);
            nf0 = *(const short8*)(fr + 8 * c0);
            nf1 = *(const short8*)(fr + 8 * c1);
            nf2 = *(const short8*)(fr + 8 * c2);
            nf3 = *(const short8*)(fr + off3);
        }

        if ((unsigned)j >= L_) continue;       // prefetch chain already advanced
        int p = poff + (j - base);
        float* rowf = out + H_OFF + (size_t)(b * NP_ + p) * R_;
        const int even = !(p & 1);             // 16B-aligned row iff p even

        float acc = 0.f;
        short8 cvs[NG] = { cv0, cv1, cv2, cv3 };
        short8 cfs[NG] = { cf0, cf1, cf2, cf3 };
        #pragma unroll
        for (int t = 0; t < NG; ++t) {
            int c = lane + t * 64;
            if (c < 198) {
                short8 vv = cvs[t];
                short8 ff = cfs[t];
                float h[8];
                #pragma unroll
                for (int e = 0; e < 8; ++e) {
                    h[e] = fmaxf(uf[t][e] + bf2f((unsigned short)vv[e])
                                          + bf2f((unsigned short)ff[e]), 0.f);
                    acc += h[e] * wf[t][e];
                }
                if (even) {
                    *(float4*)(rowf + 8 * c)     = make_float4(h[0], h[1], h[2], h[3]);
                    *(float4*)(rowf + 8 * c + 4) = make_float4(h[4], h[5], h[6], h[7]);
                } else {
                    *(float2*)(rowf + 8 * c)     = make_float2(h[0], h[1]);
                    *(float4*)(rowf + 8 * c + 2) = make_float4(h[2], h[3], h[4], h[5]);
                    *(float2*)(rowf + 8 * c + 6) = make_float2(h[6], h[7]);
                }
            } else if (c == 198) {
                short8 vv = cvs[t];
                short8 ff = cfs[t];
                float h0 = fmaxf(uf[t][0] + bf2f((unsigned short)vv[0])
                                          + bf2f((unsigned short)ff[0]), 0.f);
                float h1 = fmaxf(uf[t][1] + bf2f((unsigned short)vv[1])
                                          + bf2f((unsigned short)ff[1]), 0.f);
                *(float2*)(rowf + 1584) = make_float2(h0, h1);
                acc += h0 * wf[t][0] + h1 * wf[t][1];
            }
        }
        #pragma unroll
        for (int off = 32; off; off >>= 1) acc += __shfl_down(acc, off, 64);
        if (lane == 0)
            out[PRED_OFF + b * NP_ + p] = acc + bias;
    }
}

extern "C" void kernel_launch(void* const* d_in, const int* in_sizes, int n_in,
                              void* d_out, int out_size, void* d_ws, size_t ws_size,
                              hipStream_t stream) {
    const float* doc     = (const float*)d_in[0];
    const float* pos_emb = (const float*)d_in[1];
    const float* W1      = (const float*)d_in[2];
    const float* b1      = (const float*)d_in[3];
    const float* W2      = (const float*)d_in[4];
    const float* b2      = (const float*)d_in[5];
    float* out = (float*)d_out;

    char* ws = (char*)d_ws;
    size_t off = 0;
    unsigned short* U  = (unsigned short*)(ws + off); off += (size_t)MROWS * UVS * 2;
    unsigned short* V  = (unsigned short*)(ws + off); off += (size_t)MROWS * UVS * 2;
    unsigned short* Fb = (unsigned short*)(ws + off); off += (size_t)21 * UVS * 2;
    off = (off + 255) & ~(size_t)255;
    unsigned short* At = (unsigned short*)(ws + off); off += (size_t)MROWS * D_ * 2;
    off = (off + 255) & ~(size_t)255;
    unsigned short* Wt = (unsigned short*)(ws + off);

    prep<<<PREP_GRID, 256, 0, stream>>>(doc, pos_emb, W1, b1, At, Wt, Fb, out);
    gemm_mfma<<<416, 256, 0, stream>>>(At, Wt, U, V);
    epilogue<<<MROWS, 256, 0, stream>>>(U, V, Fb, W2, b2, out);
}

// Round 10
// 339.567 us; speedup vs baseline: 1.0324x; 1.0324x over previous
//
#include <hip/hip_runtime.h>
#include <math.h>

// Problem constants (fixed by setup_inputs)
#define B_   4
#define L_   512
#define D_   768
#define K_   10
#define P_   50
#define R_   1586          // 2*D + P
#define NP_  10642         // number of window pairs
#define MROWS 2048         // B_*L_
#define NPAD 1664          // 13*128, padded N for MFMA tiles
#define UVS  1600          // bf16 row stride for U/V/F (3200 B, 16B-aligned)

// out layout: pred [B,n] | emo_cau_pos [n,2] | h [B,n,R]  (all as float)
#define PRED_OFF 0
#define POS_OFF  (B_ * NP_)
#define H_OFF    (B_ * NP_ + NP_ * 2)

typedef __attribute__((ext_vector_type(8))) short short8;    // 8 bf16 (MFMA A/B frag)
typedef __attribute__((ext_vector_type(4))) float floatx4;   // MFMA C/D frag

__device__ __forceinline__ unsigned short f2bf(float f) {
    union { float f; unsigned int u; } a; a.f = f;
    unsigned int u = a.u;
    return (unsigned short)((u + 0x7FFF + ((u >> 16) & 1)) >> 16);  // RNE
}
__device__ __forceinline__ float bf2f(unsigned short u) {
    union { unsigned int u; float f; } a; a.u = ((unsigned int)u) << 16;
    return a.f;
}

// ---- closed-form pair indexing ----
__device__ __forceinline__ int pair_offset(int i) {
    int h = i < K_ ? i : K_;
    int off = h * (K_ + 1) + (h * (h - 1)) / 2;
    if (i > K_) {
        int fullEnd = i < (L_ - K_) ? i : (L_ - K_);
        off += (fullEnd - K_) * (2 * K_ + 1);
        if (i > L_ - K_) {
            int t = i - (L_ - K_);
            int first = 2 * K_;
            int last = L_ + K_ - (i - 1);
            off += (first + last) * t / 2;
        }
    }
    return off;
}

// ========= merged prep: convert_A | convert_W | build_F | pos =============
#define CA_BLOCKS 1536      // MROWS*D_/1024
#define CW_BLOCKS 2496      // 24*52*2
#define PREP_GRID (CA_BLOCKS + CW_BLOCKS + 21 + 2)
__global__ __launch_bounds__(256) void prep(
        const float* __restrict__ doc, const float* __restrict__ pos_emb,
        const float* __restrict__ W1, const float* __restrict__ b1,
        unsigned short* __restrict__ At, unsigned short* __restrict__ Wt,
        unsigned short* __restrict__ Fb, float* __restrict__ out) {
    __shared__ float tile[32][33];
    __shared__ float Es[P_];
    const int bid = blockIdx.x;

    if (bid < CA_BLOCKS) {                       // ---- doc -> bf16 [2048][768]
        int idx = (bid * 256 + threadIdx.x) * 4;
        float4 v = *(const float4*)(doc + idx);
        ushort4 o;
        o.x = f2bf(v.x); o.y = f2bf(v.y); o.z = f2bf(v.z); o.w = f2bf(v.w);
        *(ushort4*)(At + idx) = o;
        return;
    }
    if (bid < CA_BLOCKS + CW_BLOCKS) {           // ---- W1 -> Wt[z][n][k] bf16
        int bb = bid - CA_BLOCKS;
        int z = bb / 1248, rem = bb % 1248;
        int k0 = (rem % 24) * 32;
        int n0 = (rem / 24) * 32;
        int tx = threadIdx.x & 31, ty = threadIdx.x >> 5;
        #pragma unroll
        for (int r = 0; r < 4; ++r) {
            int k = k0 + ty + r * 8;
            int n = n0 + tx;
            tile[ty + r * 8][tx] = (n < R_) ? W1[(size_t)(z * D_ + k) * R_ + n] : 0.f;
        }
        __syncthreads();
        #pragma unroll
        for (int r = 0; r < 4; ++r) {
            int n = n0 + ty + r * 8;
            int k = k0 + tx;
            Wt[(size_t)z * NPAD * D_ + (size_t)n * D_ + k] = f2bf(tile[tx][ty + r * 8]);
        }
        return;
    }
    if (bid < CA_BLOCKS + CW_BLOCKS + 21) {      // ---- F = E @ W1[1536:,:] + b1
        int s = bid - (CA_BLOCKS + CW_BLOCKS);
        if (threadIdx.x < P_) {
            float acc = 0.f;
            #pragma unroll
            for (int r = 0; r <= 2 * K_; ++r) {
                float cnt = (float)(L_ - (r > K_ ? r - K_ : K_ - r));
                float d = (float)(s - r);
                acc += cnt * expf(-d * d) * pos_emb[r * P_ + threadIdx.x];
            }
            Es[threadIdx.x] = acc;
        }
        __syncthreads();
        for (int j = threadIdx.x; j < R_; j += 256) {
            float acc = b1[j];
            #pragma unroll 10
            for (int p = 0; p < P_; ++p)
                acc += Es[p] * W1[(2 * D_ + p) * R_ + j];
            Fb[s * UVS + j] = f2bf(acc);
        }
        return;
    }
    // ---- pos: emo_cau_pos [n,2], thread = sentence i
    int i = (bid - (CA_BLOCKS + CW_BLOCKS + 21)) * 256 + threadIdx.x;
    if (i < L_) {
        int poff = pair_offset(i);
        int jmin = i - K_ > 0 ? i - K_ : 0;
        int jmax = i + K_ < L_ - 1 ? i + K_ : L_ - 1;
        for (int j = jmin; j <= jmax; ++j) {
            int p = poff + (j - jmin);
            out[POS_OFF + p * 2 + 0] = (float)(i + 1);
            out[POS_OFF + p * 2 + 1] = (float)(j + 1);
        }
    }
}

// ===== MFMA GEMM: BK=64, dbuf + counted vmcnt + XOR swizzle + XCD locality
// (unchanged from round 6 — best measured)
#define GLOAD_LDS16(g, l) __builtin_amdgcn_global_load_lds( \
    (const __attribute__((address_space(1))) void*)(g), \
    (__attribute__((address_space(3))) void*)(l), 16, 0, 0)

__global__ __launch_bounds__(256) void gemm_mfma(
        const unsigned short* __restrict__ At,   // [2048][768] bf16
        const unsigned short* __restrict__ Wt,   // [2][1664][768] bf16 (B^T)
        unsigned short* __restrict__ U, unsigned short* __restrict__ V) {
    __shared__ unsigned short Alds[2][128 * 64];   // 2 x 16 KB
    __shared__ unsigned short Blds[2][128 * 64];

    // hardware round-robins consecutive blockIdx across XCDs: bid%8 = XCD
    const int sw  = (blockIdx.x & 7) * 52 + (blockIdx.x >> 3);   // bijective
    const int z   = sw / 208;
    const int rem = sw % 208;
    const int tileN = (rem / 16) * 128;
    const int tileM = (rem % 16) * 128;
    const unsigned short* Bt = Wt + (size_t)z * NPAD * D_;
    unsigned short* C = z ? V : U;

    const int lane = threadIdx.x & 63;
    const int w = threadIdx.x >> 6;
    const int wm = (w & 1) * 64, wn = (w >> 1) * 64;
    const int quad = lane >> 4, l16 = lane & 15;

    floatx4 acc[4][4] = {};

#define STAGE(buf, kk) do { \
        _Pragma("unroll") \
        for (int t = 0; t < 4; ++t) { \
            int chunk = t * 4 + w;               /* 0..15, wave-uniform */ \
            int r = chunk * 8 + (lane >> 3); \
            int sl = (lane & 7) ^ (lane >> 3);   /* pre-swizzled source slot */ \
            GLOAD_LDS16(At + (size_t)(tileM + r) * D_ + (kk) + sl * 8, \
                        &Alds[buf][chunk * 512]); \
            GLOAD_LDS16(Bt + (size_t)(tileN + r) * D_ + (kk) + sl * 8, \
                        &Blds[buf][chunk * 512]); \
        } } while (0)

#define KSTEP(rb, kk, dopf) do { \
        if (dopf) { \
            STAGE(rb ^ 1, (kk) + 64); \
            asm volatile("s_waitcnt vmcnt(8)" ::: "memory"); \
        } else { \
            asm volatile("s_waitcnt vmcnt(0)" ::: "memory"); \
        } \
        __builtin_amdgcn_s_barrier(); \
        __builtin_amdgcn_sched_barrier(0); \
        short8 a[4][2], b[4][2]; \
        _Pragma("unroll") \
        for (int im = 0; im < 4; ++im) \
            _Pragma("unroll") \
            for (int ks = 0; ks < 2; ++ks) \
                a[im][ks] = *(const short8*)&Alds[rb][ \
                    (wm + im * 16 + l16) * 64 + \
                    (((ks * 4 + quad) ^ (l16 & 7)) * 8)]; \
        _Pragma("unroll") \
        for (int in = 0; in < 4; ++in) \
            _Pragma("unroll") \
            for (int ks = 0; ks < 2; ++ks) \
                b[in][ks] = *(const short8*)&Blds[rb][ \
                    (wn + in * 16 + l16) * 64 + \
                    (((ks * 4 + quad) ^ (l16 & 7)) * 8)]; \
        _Pragma("unroll") \
        for (int im = 0; im < 4; ++im) \
            _Pragma("unroll") \
            for (int in = 0; in < 4; ++in) \
                _Pragma("unroll") \
                for (int ks = 0; ks < 2; ++ks) \
                    acc[im][in] = __builtin_amdgcn_mfma_f32_16x16x32_bf16( \
                        a[im][ks], b[in][ks], acc[im][in], 0, 0, 0); \
        __builtin_amdgcn_sched_barrier(0); \
        __builtin_amdgcn_s_barrier(); \
    } while (0)

    STAGE(0, 0);
    for (int k0 = 0; k0 < D_; k0 += 128) {       // 6 iters x 2 = 12 K-steps
        KSTEP(0, k0, true);
        KSTEP(1, k0 + 64, (k0 + 128) < D_);
    }
#undef KSTEP
#undef STAGE

    #pragma unroll
    for (int im = 0; im < 4; ++im) {
        #pragma unroll
        for (int in = 0; in < 4; ++in) {
            int col = tileN + wn + in * 16 + l16;
            if (col < R_) {
                #pragma unroll
                for (int r = 0; r < 4; ++r) {
                    int row = tileM + wm + im * 16 + quad * 4 + r;
                    C[(size_t)row * UVS + col] = f2bf(acc[im][in][r]);
                }
            }
        }
    }
}

// ==== epilogue (round-7 best): one BLOCK per (b,i), XCD swizzle; wave w
// takes dj = w, w+4, ... T14 reg-prefetch on V only (F is L2/L1-hot);
// U and W2 persistent in registers; float2 stores; pos writes in prep.
#define NG 4
__global__ __launch_bounds__(256) void epilogue(
        const unsigned short* __restrict__ U, const unsigned short* __restrict__ V,
        const unsigned short* __restrict__ Fb, const float* __restrict__ W2,
        const float* __restrict__ b2, float* __restrict__ out) {
    const int w    = threadIdx.x >> 6;
    const int lane = threadIdx.x & 63;
    const int sw   = (blockIdx.x & 7) * 256 + (blockIdx.x >> 3);  // bijective
    const int b    = sw >> 9;                 // /L_
    const int i    = sw & (L_ - 1);

    const unsigned short* vbase = V + (size_t)(b * L_) * UVS;
    const unsigned short* urow  = U + (size_t)(b * L_ + i) * UVS;

    // per-lane element group offsets (lane owns 8 consecutive elems)
    const int c0 = lane, c1 = lane + 64, c2 = lane + 128, c3 = lane + 192;
    const int off3 = c3 < 198 ? 8 * c3 : 1584;   // clamped tail offset

    // ---- prefetch first dj's V row (hides under U/W2 preload) ----
    int j0 = i - K_ + w;
    int jc0 = j0 < 0 ? 0 : (j0 > L_ - 1 ? L_ - 1 : j0);
    short8 nv0, nv1, nv2, nv3;
    {
        const unsigned short* vr = vbase + (size_t)jc0 * UVS;
        nv0 = *(const short8*)(vr + 8 * c0);
        nv1 = *(const short8*)(vr + 8 * c1);
        nv2 = *(const short8*)(vr + 8 * c2);
        nv3 = *(const short8*)(vr + off3);
    }

    // persistent U (f32) and W2 caches
    float uf[NG][8], wf[NG][8];
    #pragma unroll
    for (int t = 0; t < NG; ++t) {
        int c = lane + t * 64;
        if (c < 198) {
            short8 uu = *(const short8*)(urow + 8 * c);
            float4 wa = *(const float4*)(W2 + 8 * c);
            float4 wb = *(const float4*)(W2 + 8 * c + 4);
            #pragma unroll
            for (int e = 0; e < 8; ++e) uf[t][e] = bf2f((unsigned short)uu[e]);
            wf[t][0] = wa.x; wf[t][1] = wa.y; wf[t][2] = wa.z; wf[t][3] = wa.w;
            wf[t][4] = wb.x; wf[t][5] = wb.y; wf[t][6] = wb.z; wf[t][7] = wb.w;
        } else if (c == 198) {                // elems 1584,1585
            ushort2 uu = *(const ushort2*)(urow + 1584);
            float2 wt = *(const float2*)(W2 + 1584);
            uf[t][0] = bf2f(uu.x); uf[t][1] = bf2f(uu.y);
            wf[t][0] = wt.x;       wf[t][1] = wt.y;
        }
    }

    const int base = i - K_ > 0 ? i - K_ : 0;
    const int poff = pair_offset(i);
    const float bias = b2[0];

    #pragma unroll 1
    for (int dj = w; dj < 2 * K_ + 1; dj += 4) {
        int j = i - K_ + dj;

        // rotate prefetched V into "current"
        short8 cv0 = nv0, cv1 = nv1, cv2 = nv2, cv3 = nv3;

        // issue next dj's V prefetch (wave-uniform branch)
        int djn = dj + 4;
        if (djn < 2 * K_ + 1) {
            int jn = i - K_ + djn;
            int jcn = jn < 0 ? 0 : (jn > L_ - 1 ? L_ - 1 : jn);
            const unsigned short* vr = vbase + (size_t)jcn * UVS;
            nv0 = *(const short8*)(vr + 8 * c0);
            nv1 = *(const short8*)(vr + 8 * c1);
            nv2 = *(const short8*)(vr + 8 * c2);
            nv3 = *(const short8*)(vr + off3);
        }

        if ((unsigned)j >= L_) continue;       // prefetch chain already advanced
        int p = poff + (j - base);
        const unsigned short* frow = Fb + (size_t)dj * UVS;
        float2* h2 = (float2*)(out + H_OFF + (size_t)(b * NP_ + p) * R_);

        float acc = 0.f;
        short8 cvs[NG] = { cv0, cv1, cv2, cv3 };  // static-indexed below
        #pragma unroll
        for (int t = 0; t < NG; ++t) {
            int c = lane + t * 64;
            if (c < 198) {
                short8 vv = cvs[t];
                short8 ff = *(const short8*)(frow + 8 * c);
                float h[8];
                #pragma unroll
                for (int e = 0; e < 8; ++e) {
                    h[e] = fmaxf(uf[t][e] + bf2f((unsigned short)vv[e])
                                          + bf2f((unsigned short)ff[e]), 0.f);
                    acc += h[e] * wf[t][e];
                }
                #pragma unroll
                for (int q = 0; q < 4; ++q)
                    h2[4 * c + q] = make_float2(h[2 * q], h[2 * q + 1]);
            } else if (c == 198) {
                short8 vv = cvs[t];               // holds elems 1584.. (tail)
                ushort2 ff = *(const ushort2*)(frow + 1584);
                float h0 = fmaxf(uf[t][0] + bf2f((unsigned short)vv[0]) + bf2f(ff.x), 0.f);
                float h1 = fmaxf(uf[t][1] + bf2f((unsigned short)vv[1]) + bf2f(ff.y), 0.f);
                h2[792] = make_float2(h0, h1);
                acc += h0 * wf[t][0] + h1 * wf[t][1];
            }
        }
        #pragma unroll
        for (int off = 32; off; off >>= 1) acc += __shfl_down(acc, off, 64);
        if (lane == 0)
            out[PRED_OFF + b * NP_ + p] = acc + bias;
    }
}

extern "C" void kernel_launch(void* const* d_in, const int* in_sizes, int n_in,
                              void* d_out, int out_size, void* d_ws, size_t ws_size,
                              hipStream_t stream) {
    const float* doc     = (const float*)d_in[0];
    const float* pos_emb = (const float*)d_in[1];
    const float* W1      = (const float*)d_in[2];
    const float* b1      = (const float*)d_in[3];
    const float* W2      = (const float*)d_in[4];
    const float* b2      = (const float*)d_in[5];
    float* out = (float*)d_out;

    char* ws = (char*)d_ws;
    size_t off = 0;
    unsigned short* U  = (unsigned short*)(ws + off); off += (size_t)MROWS * UVS * 2;
    unsigned short* V  = (unsigned short*)(ws + off); off += (size_t)MROWS * UVS * 2;
    unsigned short* Fb = (unsigned short*)(ws + off); off += (size_t)21 * UVS * 2;
    off = (off + 255) & ~(size_t)255;
    unsigned short* At = (unsigned short*)(ws + off); off += (size_t)MROWS * D_ * 2;
    off = (off + 255) & ~(size_t)255;
    unsigned short* Wt = (unsigned short*)(ws + off);

    prep<<<PREP_GRID, 256, 0, stream>>>(doc, pos_emb, W1, b1, At, Wt, Fb, out);
    gemm_mfma<<<416, 256, 0, stream>>>(At, Wt, U, V);
    epilogue<<<MROWS, 256, 0, stream>>>(U, V, Fb, W2, b2, out);
}